// Round 6
// baseline (573.480 us; speedup 1.0000x reference)
//
#include <hip/hip_runtime.h>
#include <hip/hip_cooperative_groups.h>

namespace cg = cooperative_groups;

#define D 128
#define NHB 256            // cooperative grid size = hist/scatter rows
#define MAXBUC 2048        // LDS bucket counters (N <= 131072)
#define WP 136             // LDS pitch in bf16 elems (breaks 256B-stride bank aliasing)

typedef __attribute__((ext_vector_type(8))) short bf16x8;
typedef __attribute__((ext_vector_type(4))) float f32x4;

__device__ inline ushort f2b(float f) {   // fp32 -> bf16 RNE
  unsigned u = __float_as_uint(f);
  return (ushort)((u + 0x7fffu + ((u >> 16) & 1u)) >> 16);
}

// ---------------- MFMA GEMM: g(bf16) = x @ W^T + b   (no dis; independent) ----------------
// A[m][k]: rows of x, direct global loads (line-coalesced: 16 rows x 64B lines).
// B[k][n] = W[n][k]: lane holds 8 consecutive k of W row n — contiguous as stored.
__global__ __launch_bounds__(256) void k_gemm3(
    const float* __restrict__ x, const float* __restrict__ W,
    const float* __restrict__ bias, ushort* __restrict__ g, int n) {
  __shared__ ushort sw[128 * WP];   // 34.8 KB; reused as epilogue staging
  const int tid = threadIdx.x;
  const int row0 = blockIdx.x * 64;

  // stage W (fp32 -> bf16)
  for (int i = tid; i < 128 * 32; i += 256) {
    int o = i >> 5, kg = i & 31;
    float4 v = ((const float4*)W)[i];
    ushort4 h;
    h.x = f2b(v.x); h.y = f2b(v.y); h.z = f2b(v.z); h.w = f2b(v.w);
    *(ushort4*)(&sw[o * WP + kg * 4]) = h;
  }
  __syncthreads();

  const int wid = tid >> 6, lane = tid & 63;
  const int wr0 = wid * 16;              // wave's 16-row slice of 64-row tile
  const int col = lane & 15, quad = lane >> 4;
  int arow = row0 + wr0 + col;
  if (arow >= n) arow = n - 1;           // clamp loads; stores are guarded
  const float4* xrow = (const float4*)(x + (size_t)arow * D);

  f32x4 acc[8] = {};
#pragma unroll
  for (int s = 0; s < 4; ++s) {          // K = 4 x 32
    float4 v0 = xrow[s * 8 + quad * 2];
    float4 v1 = xrow[s * 8 + quad * 2 + 1];
    bf16x8 a;
    a[0] = f2b(v0.x); a[1] = f2b(v0.y); a[2] = f2b(v0.z); a[3] = f2b(v0.w);
    a[4] = f2b(v1.x); a[5] = f2b(v1.y); a[6] = f2b(v1.z); a[7] = f2b(v1.w);
#pragma unroll
    for (int t = 0; t < 8; ++t) {        // 8 col-tiles of 16
      bf16x8 bfr = *(const bf16x8*)(&sw[(t * 16 + col) * WP + s * 32 + quad * 8]);
      acc[t] = __builtin_amdgcn_mfma_f32_16x16x32_bf16(a, bfr, acc[t], 0, 0, 0);
    }
  }

  __syncthreads();   // all waves done reading sw; reuse for output bounce
#pragma unroll
  for (int t = 0; t < 8; ++t) {
    float bcol = bias[t * 16 + col];
#pragma unroll
    for (int r = 0; r < 4; ++r) {
      int row = wr0 + quad * 4 + r;      // C layout: col=lane&15, row=quad*4+reg
      sw[row * WP + t * 16 + col] = f2b(acc[t][r] + bcol);
    }
  }
  __syncthreads();
  for (int i = tid; i < 64 * 16; i += 256) {   // 64 rows x 16 chunks of 16 B
    int r = i >> 4, c = i & 15;
    int gr = row0 + r;
    if (gr < n)
      *(uint4*)(&g[(size_t)gr * D + c * 8]) = *(const uint4*)(&sw[r * WP + c * 8]);
  }
}

// ---------------- cooperative build: hist -> coltotal -> scan -> blockstart
//                  -> scatter -> per-bucket counting sort (srcs, nodeoff, dis) --------------
__global__ __launch_bounds__(256) void k_build(
    const int* __restrict__ ei, int* __restrict__ hist, int* __restrict__ tot,
    int* __restrict__ boff, int* __restrict__ bstart, int* __restrict__ entries,
    int* __restrict__ srcs, int* __restrict__ nodeoff, float* __restrict__ dis,
    int E, int N, int nbuc) {
  cg::grid_group grid = cg::this_grid();
  __shared__ int smem[MAXBUC];
  __shared__ int srun;
  const int tid = threadIdx.x;
  const int nb = gridDim.x;              // == NHB
  const int gtid = blockIdx.x * 256 + tid;
  const int per = (E + nb - 1) / nb;
  const int e0 = blockIdx.x * per, e1 = min(E, e0 + per);

  // P0: per-block bucket histogram
  for (int i = tid; i < nbuc; i += 256) smem[i] = 0;
  __syncthreads();
  for (int e = e0 + tid; e < e1; e += 256) {
    int r = ei[e], c = ei[E + e];
    atomicAdd(&smem[c >> 6], 1);
    atomicAdd(&smem[r >> 6], 1);
  }
  __syncthreads();
  for (int i = tid; i < nbuc; i += 256) hist[blockIdx.x * nbuc + i] = smem[i];
  __threadfence();
  grid.sync();

  // P1: column totals
  for (int b = gtid; b < nbuc; b += nb * 256) {
    int s = 0;
    for (int j = 0; j < nb; ++j) s += hist[j * nbuc + b];
    tot[b] = s;
  }
  __threadfence();
  grid.sync();

  // P2: exclusive scan of tot -> boff (block 0 only)
  if (blockIdx.x == 0) {
    if (tid == 0) srun = 0;
    __syncthreads();
    for (int base = 0; base < nbuc; base += 256) {
      int i = base + tid;
      int v = (i < nbuc) ? tot[i] : 0;
      smem[tid] = v;
      __syncthreads();
      for (int o = 1; o < 256; o <<= 1) {
        int t = (tid >= o) ? smem[tid - o] : 0;
        __syncthreads();
        smem[tid] += t;
        __syncthreads();
      }
      if (i < nbuc) boff[i] = srun + smem[tid] - v;
      __syncthreads();
      if (tid == 0) srun += smem[255];
      __syncthreads();
    }
    if (tid == 0) boff[nbuc] = srun;
  }
  __threadfence();
  grid.sync();

  // P3: blockstart[j][b] = boff[b] + prefix_j(hist[:,b])
  for (int b = blockIdx.x; b < nbuc; b += nb) {
    int v = hist[tid * nbuc + b];
    smem[tid] = v;
    __syncthreads();
    for (int o = 1; o < 256; o <<= 1) {
      int t = (tid >= o) ? smem[tid - o] : 0;
      __syncthreads();
      smem[tid] += t;
      __syncthreads();
    }
    bstart[tid * nbuc + b] = boff[b] + smem[tid] - v;
    __syncthreads();
  }
  __threadfence();
  grid.sync();

  // P4: scatter packed entries (src<<6 | dest&63) via LDS cursors
  for (int i = tid; i < nbuc; i += 256) smem[i] = bstart[blockIdx.x * nbuc + i];
  __syncthreads();
  for (int e = e0 + tid; e < e1; e += 256) {
    int r = ei[e], c = ei[E + e];
    int p1 = atomicAdd(&smem[c >> 6], 1);
    entries[p1] = (r << 6) | (c & 63);
    int p2 = atomicAdd(&smem[r >> 6], 1);
    entries[p2] = (c << 6) | (r & 63);
  }
  __threadfence();
  grid.sync();

  // P5: per-bucket counting sort by dest -> srcs contiguous per node; nodeoff; dis
  for (int b = blockIdx.x; b < nbuc; b += nb) {
    const int s0 = boff[b], e0b = boff[b + 1];
    if (tid < 64) smem[tid] = 0;
    __syncthreads();
    for (int i = s0 + tid; i < e0b; i += 256)
      atomicAdd(&smem[entries[i] & 63], 1);
    __syncthreads();
    int v = (tid < 64) ? smem[tid] : 0;
    if (tid < 64) smem[64 + tid] = v;
    __syncthreads();
    for (int o = 1; o < 64; o <<= 1) {
      int t = (tid < 64 && tid >= o) ? smem[64 + tid - o] : 0;
      __syncthreads();
      if (tid < 64) smem[64 + tid] += t;
      __syncthreads();
    }
    if (tid < 64) {
      int start = s0 + smem[64 + tid] - v;
      smem[tid] = start;                 // becomes cursor
      int gn = b * 64 + tid;
      if (gn < N) {
        nodeoff[gn] = start;
        dis[gn] = rsqrtf((float)(v + 1));  // +1 self loop
        if (gn == N - 1) nodeoff[N] = e0b;
      }
    }
    __syncthreads();
    for (int i = s0 + tid; i < e0b; i += 256) {
      int en = entries[i];
      int p = atomicAdd(&smem[en & 63], 1);
      srcs[p] = en >> 6;
    }
    __syncthreads();
  }
}

// ---------------- pull aggregation, ILP-8, dis folded into gather ----------------
// out[v] = relu(dis[v] * (dis[v]*g[v] + sum_u dis[u]*g[u]))
__global__ __launch_bounds__(256) void k_agg5(const int* __restrict__ nodeoff,
                                              const int* __restrict__ srcs,
                                              const uint* __restrict__ g32,
                                              const float* __restrict__ dis,
                                              float* __restrict__ out, int N) {
  int w = blockIdx.x * 4 + (threadIdx.x >> 6);
  if (w >= N) return;
  int lane = threadIdx.x & 63;

  float dv = dis[w];
  uint us = g32[(size_t)w * 64 + lane];
  float ax = __uint_as_float(us << 16) * dv;          // self: dis_v * g_v
  float ay = __uint_as_float(us & 0xffff0000u) * dv;

  int s = nodeoff[w];
  int e = nodeoff[w + 1];
  for (int base = s; base < e; base += 64) {
    int cnt = e - base; if (cnt > 64) cnt = 64;
    int idx = base + lane;
    int my = (idx < e) ? srcs[idx] : 0;
    float dl = (idx < e) ? dis[my] : 0.f;
    int k = 0;
    for (; k + 7 < cnt; k += 8) {
      int u0 = __shfl(my, k);     int u1 = __shfl(my, k + 1);
      int u2 = __shfl(my, k + 2); int u3 = __shfl(my, k + 3);
      int u4 = __shfl(my, k + 4); int u5 = __shfl(my, k + 5);
      int u6 = __shfl(my, k + 6); int u7 = __shfl(my, k + 7);
      float d0 = __shfl(dl, k);     float d1 = __shfl(dl, k + 1);
      float d2 = __shfl(dl, k + 2); float d3 = __shfl(dl, k + 3);
      float d4 = __shfl(dl, k + 4); float d5 = __shfl(dl, k + 5);
      float d6 = __shfl(dl, k + 6); float d7 = __shfl(dl, k + 7);
      uint a0 = g32[(size_t)u0 * 64 + lane];
      uint a1 = g32[(size_t)u1 * 64 + lane];
      uint a2 = g32[(size_t)u2 * 64 + lane];
      uint a3 = g32[(size_t)u3 * 64 + lane];
      uint a4 = g32[(size_t)u4 * 64 + lane];
      uint a5 = g32[(size_t)u5 * 64 + lane];
      uint a6 = g32[(size_t)u6 * 64 + lane];
      uint a7 = g32[(size_t)u7 * 64 + lane];
      ax = fmaf(d0, __uint_as_float(a0 << 16), ax);
      ay = fmaf(d0, __uint_as_float(a0 & 0xffff0000u), ay);
      ax = fmaf(d1, __uint_as_float(a1 << 16), ax);
      ay = fmaf(d1, __uint_as_float(a1 & 0xffff0000u), ay);
      ax = fmaf(d2, __uint_as_float(a2 << 16), ax);
      ay = fmaf(d2, __uint_as_float(a2 & 0xffff0000u), ay);
      ax = fmaf(d3, __uint_as_float(a3 << 16), ax);
      ay = fmaf(d3, __uint_as_float(a3 & 0xffff0000u), ay);
      ax = fmaf(d4, __uint_as_float(a4 << 16), ax);
      ay = fmaf(d4, __uint_as_float(a4 & 0xffff0000u), ay);
      ax = fmaf(d5, __uint_as_float(a5 << 16), ax);
      ay = fmaf(d5, __uint_as_float(a5 & 0xffff0000u), ay);
      ax = fmaf(d6, __uint_as_float(a6 << 16), ax);
      ay = fmaf(d6, __uint_as_float(a6 & 0xffff0000u), ay);
      ax = fmaf(d7, __uint_as_float(a7 << 16), ax);
      ay = fmaf(d7, __uint_as_float(a7 & 0xffff0000u), ay);
    }
    for (; k < cnt; ++k) {
      int u = __shfl(my, k);
      float du = __shfl(dl, k);
      uint a = g32[(size_t)u * 64 + lane];
      ax = fmaf(du, __uint_as_float(a << 16), ax);
      ay = fmaf(du, __uint_as_float(a & 0xffff0000u), ay);
    }
  }
  float2 o;
  o.x = fmaxf(ax * dv, 0.f);
  o.y = fmaxf(ay * dv, 0.f);
  ((float2*)out)[(size_t)w * 64 + lane] = o;
}

extern "C" void kernel_launch(void* const* d_in, const int* in_sizes, int n_in,
                              void* d_out, int out_size, void* d_ws, size_t ws_size,
                              hipStream_t stream) {
  const float* x  = (const float*)d_in[0];
  const int*   ei = (const int*)d_in[1];
  const float* W  = (const float*)d_in[2];
  const float* b  = (const float*)d_in[3];
  float* out = (float*)d_out;

  int N = in_sizes[0] / D;
  int E = in_sizes[1] / 2;
  int NBUC = (N + 63) / 64;                  // 1563 for N=100k (<= MAXBUC)

  char* ws = (char*)d_ws;
  size_t off = 0;
  ushort* g    = (ushort*)(ws + off); off += (size_t)N * D * 2;        // 25.6 MB
  off = (off + 255) & ~(size_t)255;
  float* dis   = (float*)(ws + off);  off += (size_t)N * 4;
  off = (off + 255) & ~(size_t)255;
  int* nodeoff = (int*)(ws + off);    off += (size_t)(N + 1) * 4;
  off = (off + 255) & ~(size_t)255;
  int* tot     = (int*)(ws + off);    off += (size_t)NBUC * 4;
  int* boff    = (int*)(ws + off);    off += (size_t)(NBUC + 1) * 4;
  off = (off + 255) & ~(size_t)255;
  int* hist    = (int*)(ws + off);    off += (size_t)NHB * NBUC * 4;   // 1.6 MB
  off = (off + 255) & ~(size_t)255;
  int* bstart  = (int*)(ws + off);    off += (size_t)NHB * NBUC * 4;   // 1.6 MB
  off = (off + 255) & ~(size_t)255;
  int* entries = (int*)(ws + off);    off += (size_t)2 * E * 4;        // 6.4 MB
  off = (off + 255) & ~(size_t)255;
  int* srcs    = (int*)(ws + off);    off += (size_t)2 * E * 4;        // 6.4 MB

  // 1) GEMM (independent of graph build)
  k_gemm3<<<NBUC, 256, 0, stream>>>(x, W, b, g, N);

  // 2) whole graph build in one cooperative kernel
  void* args[] = {(void*)&ei, (void*)&hist, (void*)&tot, (void*)&boff,
                  (void*)&bstart, (void*)&entries, (void*)&srcs,
                  (void*)&nodeoff, (void*)&dis, (void*)&E, (void*)&N, (void*)&NBUC};
  hipLaunchCooperativeKernel((void*)k_build, dim3(NHB), dim3(256), args, 0, stream);

  // 3) aggregation
  k_agg5<<<(N + 3) / 4, 256, 0, stream>>>(nodeoff, srcs, (const uint*)g, dis, out, N);
}

// Round 7
// 236.631 us; speedup vs baseline: 2.4235x; 2.4235x over previous
//
#include <hip/hip_runtime.h>

#define D 128
#define NHB 256            // blocks for hist/scatter passes (= hist rows)
#define MAXBUC 2048        // LDS bucket counters (N <= 131072)
#define WP 136             // LDS pitch in bf16 elems (breaks 256B-stride bank aliasing)

typedef __attribute__((ext_vector_type(8))) short bf16x8;
typedef __attribute__((ext_vector_type(4))) float f32x4;

__device__ inline ushort f2b(float f) {   // fp32 -> bf16 RNE
  unsigned u = __float_as_uint(f);
  return (ushort)((u + 0x7fffu + ((u >> 16) & 1u)) >> 16);
}

// ---------------- MFMA GEMM: g(bf16) = x @ W^T + b   (independent of build) ----------------
__global__ __launch_bounds__(256) void k_gemm3(
    const float* __restrict__ x, const float* __restrict__ W,
    const float* __restrict__ bias, ushort* __restrict__ g, int n) {
  __shared__ ushort sw[128 * WP];   // 34.8 KB; reused as epilogue staging
  const int tid = threadIdx.x;
  const int row0 = blockIdx.x * 64;

  for (int i = tid; i < 128 * 32; i += 256) {   // stage W fp32->bf16
    int o = i >> 5, kg = i & 31;
    float4 v = ((const float4*)W)[i];
    ushort4 h;
    h.x = f2b(v.x); h.y = f2b(v.y); h.z = f2b(v.z); h.w = f2b(v.w);
    *(ushort4*)(&sw[o * WP + kg * 4]) = h;
  }
  __syncthreads();

  const int wid = tid >> 6, lane = tid & 63;
  const int wr0 = wid * 16;
  const int col = lane & 15, quad = lane >> 4;
  int arow = row0 + wr0 + col;
  if (arow >= n) arow = n - 1;           // clamp loads; stores guarded
  const float4* xrow = (const float4*)(x + (size_t)arow * D);

  f32x4 acc[8] = {};
#pragma unroll
  for (int s = 0; s < 4; ++s) {          // K = 4 x 32
    float4 v0 = xrow[s * 8 + quad * 2];
    float4 v1 = xrow[s * 8 + quad * 2 + 1];
    bf16x8 a;
    a[0] = f2b(v0.x); a[1] = f2b(v0.y); a[2] = f2b(v0.z); a[3] = f2b(v0.w);
    a[4] = f2b(v1.x); a[5] = f2b(v1.y); a[6] = f2b(v1.z); a[7] = f2b(v1.w);
#pragma unroll
    for (int t = 0; t < 8; ++t) {
      bf16x8 bfr = *(const bf16x8*)(&sw[(t * 16 + col) * WP + s * 32 + quad * 8]);
      acc[t] = __builtin_amdgcn_mfma_f32_16x16x32_bf16(a, bfr, acc[t], 0, 0, 0);
    }
  }

  __syncthreads();   // reuse sw for output bounce
#pragma unroll
  for (int t = 0; t < 8; ++t) {
    float bcol = bias[t * 16 + col];
#pragma unroll
    for (int r = 0; r < 4; ++r) {
      int row = wr0 + quad * 4 + r;      // C layout: col=lane&15, row=quad*4+reg
      sw[row * WP + t * 16 + col] = f2b(acc[t][r] + bcol);
    }
  }
  __syncthreads();
  for (int i = tid; i < 64 * 16; i += 256) {
    int r = i >> 4, c = i & 15;
    int gr = row0 + r;
    if (gr < n)
      *(uint4*)(&g[(size_t)gr * D + c * 8]) = *(const uint4*)(&sw[r * WP + c * 8]);
  }
}

// ---------------- P0: per-block bucket histogram, layout hist[b][j] ----------------
__global__ __launch_bounds__(256) void k_hist(const int* __restrict__ ei,
                                              int* __restrict__ hist,
                                              int* __restrict__ ctr, int E, int nbuc) {
  __shared__ int h[MAXBUC];
  if (blockIdx.x == 0 && threadIdx.x == 0) *ctr = 0;   // for k_alloc
  for (int i = threadIdx.x; i < nbuc; i += 256) h[i] = 0;
  __syncthreads();
  int per = (E + NHB - 1) / NHB;
  int e0 = blockIdx.x * per, e1 = min(E, e0 + per);
  for (int e = e0 + threadIdx.x; e < e1; e += 256) {
    int r = ei[e], c = ei[E + e];
    atomicAdd(&h[c >> 6], 1);
    atomicAdd(&h[r >> 6], 1);
  }
  __syncthreads();
  for (int i = threadIdx.x; i < nbuc; i += 256)
    hist[i * NHB + blockIdx.x] = h[i];
}

// ---------------- P1: one wave per bucket — wave-scan hist column, atomic region alloc ----
__global__ __launch_bounds__(256) void k_alloc(const int* __restrict__ hist,
                                               int* __restrict__ bstart,
                                               int* __restrict__ boff,
                                               int* __restrict__ bend,
                                               int* __restrict__ ctr, int nbuc) {
  int b = blockIdx.x * 4 + (threadIdx.x >> 6);
  if (b >= nbuc) return;
  int lane = threadIdx.x & 63;
  int4 v = ((const int4*)(hist + (size_t)b * NHB))[lane];   // rows 4l..4l+3, coalesced
  int p1 = v.x, p2 = p1 + v.y, p3 = p2 + v.z, s = p3 + v.w;
  int incl = s;
#pragma unroll
  for (int o = 1; o < 64; o <<= 1) {
    int t = __shfl_up(incl, o);
    if (lane >= o) incl += t;
  }
  int tot = __shfl(incl, 63);
  int base = 0;
  if (lane == 63) base = atomicAdd(ctr, tot);     // disjoint region, arbitrary order
  base = __shfl(base, 63);
  if (lane == 63) { boff[b] = base; bend[b] = base + tot; }
  int excl = base + incl - s;
  int4 w;
  w.x = excl; w.y = excl + p1; w.z = excl + p2; w.w = excl + p3;
  ((int4*)(bstart + (size_t)b * NHB))[lane] = w;
}

// ---------------- P2: scatter packed entries (src<<6 | dest&63) via LDS cursors ----------
__global__ __launch_bounds__(256) void k_scatter2(const int* __restrict__ ei,
                                                  const int* __restrict__ bstart,
                                                  int* __restrict__ entries,
                                                  int E, int nbuc) {
  __shared__ int cur[MAXBUC];
  for (int i = threadIdx.x; i < nbuc; i += 256)
    cur[i] = bstart[(size_t)i * NHB + blockIdx.x];
  __syncthreads();
  int per = (E + NHB - 1) / NHB;
  int e0 = blockIdx.x * per, e1 = min(E, e0 + per);
  for (int e = e0 + threadIdx.x; e < e1; e += 256) {
    int r = ei[e], c = ei[E + e];
    int p1 = atomicAdd(&cur[c >> 6], 1);
    entries[p1] = (r << 6) | (c & 63);
    int p2 = atomicAdd(&cur[r >> 6], 1);
    entries[p2] = (c << 6) | (r & 63);
  }
}

// ---------------- P3: per-bucket counting sort by dest -> srcs; nodese(start,cnt); dis ----
__global__ __launch_bounds__(256) void k_sortbuc(const int* __restrict__ entries,
                                                 const int* __restrict__ boff,
                                                 const int* __restrict__ bend,
                                                 int* __restrict__ srcs,
                                                 int2* __restrict__ nodese,
                                                 float* __restrict__ dis, int N) {
  __shared__ int bin[64];
  __shared__ int sc[64];
  const int b = blockIdx.x;
  const int s = boff[b], e = bend[b];

  if (threadIdx.x < 64) bin[threadIdx.x] = 0;
  __syncthreads();
  for (int i = s + threadIdx.x; i < e; i += 256)
    atomicAdd(&bin[entries[i] & 63], 1);
  __syncthreads();

  int v = (threadIdx.x < 64) ? bin[threadIdx.x] : 0;
  if (threadIdx.x < 64) sc[threadIdx.x] = v;
  __syncthreads();
  for (int o = 1; o < 64; o <<= 1) {
    int t = (threadIdx.x < 64 && threadIdx.x >= (unsigned)o) ? sc[threadIdx.x - o] : 0;
    __syncthreads();
    if (threadIdx.x < 64) sc[threadIdx.x] += t;
    __syncthreads();
  }
  if (threadIdx.x < 64) {
    int start = s + sc[threadIdx.x] - v;
    bin[threadIdx.x] = start;                  // becomes cursor
    int gn = b * 64 + threadIdx.x;
    if (gn < N) {
      nodese[gn] = make_int2(start, v);
      dis[gn] = rsqrtf((float)(v + 1));        // +1 self loop
    }
  }
  __syncthreads();

  for (int i = s + threadIdx.x; i < e; i += 256) {
    int en = entries[i];
    int p = atomicAdd(&bin[en & 63], 1);
    srcs[p] = en >> 6;
  }
}

// ---------------- P4: pull aggregation, ILP-8, dis folded into gather ----------------
__global__ __launch_bounds__(256) void k_agg5(const int2* __restrict__ nodese,
                                              const int* __restrict__ srcs,
                                              const uint* __restrict__ g32,
                                              const float* __restrict__ dis,
                                              float* __restrict__ out, int N) {
  int w = blockIdx.x * 4 + (threadIdx.x >> 6);
  if (w >= N) return;
  int lane = threadIdx.x & 63;

  float dv = dis[w];
  uint us = g32[(size_t)w * 64 + lane];
  float ax = __uint_as_float(us << 16) * dv;          // self: dis_v * g_v
  float ay = __uint_as_float(us & 0xffff0000u) * dv;

  int2 se = nodese[w];
  int s = se.x, e = se.x + se.y;
  for (int base = s; base < e; base += 64) {
    int cnt = e - base; if (cnt > 64) cnt = 64;
    int idx = base + lane;
    int my = (idx < e) ? srcs[idx] : 0;
    float dl = (idx < e) ? dis[my] : 0.f;
    int k = 0;
    for (; k + 7 < cnt; k += 8) {
      int u0 = __shfl(my, k);     int u1 = __shfl(my, k + 1);
      int u2 = __shfl(my, k + 2); int u3 = __shfl(my, k + 3);
      int u4 = __shfl(my, k + 4); int u5 = __shfl(my, k + 5);
      int u6 = __shfl(my, k + 6); int u7 = __shfl(my, k + 7);
      float d0 = __shfl(dl, k);     float d1 = __shfl(dl, k + 1);
      float d2 = __shfl(dl, k + 2); float d3 = __shfl(dl, k + 3);
      float d4 = __shfl(dl, k + 4); float d5 = __shfl(dl, k + 5);
      float d6 = __shfl(dl, k + 6); float d7 = __shfl(dl, k + 7);
      uint a0 = g32[(size_t)u0 * 64 + lane];
      uint a1 = g32[(size_t)u1 * 64 + lane];
      uint a2 = g32[(size_t)u2 * 64 + lane];
      uint a3 = g32[(size_t)u3 * 64 + lane];
      uint a4 = g32[(size_t)u4 * 64 + lane];
      uint a5 = g32[(size_t)u5 * 64 + lane];
      uint a6 = g32[(size_t)u6 * 64 + lane];
      uint a7 = g32[(size_t)u7 * 64 + lane];
      ax = fmaf(d0, __uint_as_float(a0 << 16), ax);
      ay = fmaf(d0, __uint_as_float(a0 & 0xffff0000u), ay);
      ax = fmaf(d1, __uint_as_float(a1 << 16), ax);
      ay = fmaf(d1, __uint_as_float(a1 & 0xffff0000u), ay);
      ax = fmaf(d2, __uint_as_float(a2 << 16), ax);
      ay = fmaf(d2, __uint_as_float(a2 & 0xffff0000u), ay);
      ax = fmaf(d3, __uint_as_float(a3 << 16), ax);
      ay = fmaf(d3, __uint_as_float(a3 & 0xffff0000u), ay);
      ax = fmaf(d4, __uint_as_float(a4 << 16), ax);
      ay = fmaf(d4, __uint_as_float(a4 & 0xffff0000u), ay);
      ax = fmaf(d5, __uint_as_float(a5 << 16), ax);
      ay = fmaf(d5, __uint_as_float(a5 & 0xffff0000u), ay);
      ax = fmaf(d6, __uint_as_float(a6 << 16), ax);
      ay = fmaf(d6, __uint_as_float(a6 & 0xffff0000u), ay);
      ax = fmaf(d7, __uint_as_float(a7 << 16), ax);
      ay = fmaf(d7, __uint_as_float(a7 & 0xffff0000u), ay);
    }
    for (; k < cnt; ++k) {
      int u = __shfl(my, k);
      float du = __shfl(dl, k);
      uint a = g32[(size_t)u * 64 + lane];
      ax = fmaf(du, __uint_as_float(a << 16), ax);
      ay = fmaf(du, __uint_as_float(a & 0xffff0000u), ay);
    }
  }
  float2 o;
  o.x = fmaxf(ax * dv, 0.f);
  o.y = fmaxf(ay * dv, 0.f);
  ((float2*)out)[(size_t)w * 64 + lane] = o;
}

extern "C" void kernel_launch(void* const* d_in, const int* in_sizes, int n_in,
                              void* d_out, int out_size, void* d_ws, size_t ws_size,
                              hipStream_t stream) {
  const float* x  = (const float*)d_in[0];
  const int*   ei = (const int*)d_in[1];
  const float* W  = (const float*)d_in[2];
  const float* b  = (const float*)d_in[3];
  float* out = (float*)d_out;

  const int N = in_sizes[0] / D;
  const int E = in_sizes[1] / 2;
  const int NBUC = (N + 63) / 64;            // 1563 for N=100k (<= MAXBUC)

  char* ws = (char*)d_ws;
  size_t off = 0;
  ushort* g    = (ushort*)(ws + off); off += (size_t)N * D * 2;        // 25.6 MB
  off = (off + 255) & ~(size_t)255;
  float* dis   = (float*)(ws + off);  off += (size_t)N * 4;
  off = (off + 255) & ~(size_t)255;
  int2* nodese = (int2*)(ws + off);   off += (size_t)N * 8;
  off = (off + 255) & ~(size_t)255;
  int* boff    = (int*)(ws + off);    off += (size_t)NBUC * 4;
  int* bend    = (int*)(ws + off);    off += (size_t)NBUC * 4;
  int* ctr     = (int*)(ws + off);    off += 256;
  off = (off + 255) & ~(size_t)255;
  int* hist    = (int*)(ws + off);    off += (size_t)NBUC * NHB * 4;   // 1.6 MB
  off = (off + 255) & ~(size_t)255;
  int* bstart  = (int*)(ws + off);    off += (size_t)NBUC * NHB * 4;   // 1.6 MB
  off = (off + 255) & ~(size_t)255;
  int* entries = (int*)(ws + off);    off += (size_t)2 * E * 4;        // 6.4 MB
  off = (off + 255) & ~(size_t)255;
  int* srcs    = (int*)(ws + off);    off += (size_t)2 * E * 4;        // 6.4 MB

  k_gemm3<<<NBUC, 256, 0, stream>>>(x, W, b, g, N);
  k_hist<<<NHB, 256, 0, stream>>>(ei, hist, ctr, E, NBUC);
  k_alloc<<<(NBUC + 3) / 4, 256, 0, stream>>>(hist, bstart, boff, bend, ctr, NBUC);
  k_scatter2<<<NHB, 256, 0, stream>>>(ei, bstart, entries, E, NBUC);
  k_sortbuc<<<NBUC, 256, 0, stream>>>(entries, boff, bend, srcs, nodese, dis, N);
  k_agg5<<<(N + 3) / 4, 256, 0, stream>>>(nodese, srcs, (const uint*)g, dis, out, N);
}